// Round 5
// baseline (1313.576 us; speedup 1.0000x reference)
//
#include <hip/hip_runtime.h>
#include <hip/hip_bf16.h>

#define FEAT 40960
#define NH1  256
#define CAP  64     // list capacity per row-side; reference has <=30 nonzeros

typedef float vfloat4 __attribute__((ext_vector_type(4)));

// ---------------------------------------------------------------------------
// Kernel 0: zero the per-row-side nonzero counters (ws is poisoned 0xAA).
// ---------------------------------------------------------------------------
__global__ __launch_bounds__(256) void zero_cnt(int* __restrict__ cnt, int n) {
    const int i = blockIdx.x * 256 + threadIdx.x;
    if (i < n) cnt[i] = 0;
}

// ---------------------------------------------------------------------------
// Kernel A: transpose ft_w [256][40960] -> ft_wt [40960][256]
// ---------------------------------------------------------------------------
__global__ __launch_bounds__(256) void transpose_ftw(const float* __restrict__ ft_w,
                                                     float* __restrict__ ft_wt) {
    __shared__ float tile[32][33];
    const int i0 = blockIdx.x * 32;
    const int h0 = blockIdx.y * 32;
    const int tx = threadIdx.x;
    const int ty = threadIdx.y;
#pragma unroll
    for (int j = 0; j < 4; ++j)
        tile[ty + j * 8][tx] = ft_w[(size_t)(h0 + ty + j * 8) * FEAT + i0 + tx];
    __syncthreads();
#pragma unroll
    for (int j = 0; j < 4; ++j)
        ft_wt[(size_t)(i0 + ty + j * 8) * NH1 + h0 + tx] = tile[tx][ty + j * 8];
}

// ---------------------------------------------------------------------------
// Kernel B: pure streaming scan in fill-kernel shape. Grid-stride float4
// loop; wave-uniform __any skips the rare compaction path (83% of wave
// iterations are all-zero). Nonzeros appended to per-row lists in ws via
// global atomics (~245K total, ~0 contention).
// blockIdx.y selects side (0 = white, 1 = black).
// ---------------------------------------------------------------------------
__global__ __launch_bounds__(256) void scan_nz(
    const float* __restrict__ wf,
    const float* __restrict__ bfeat,
    int*   __restrict__ cnt,    // [2*B]
    int*   __restrict__ idxl,   // [2*B][CAP]
    float* __restrict__ vall,   // [2*B][CAP]
    int B)
{
    const int side = blockIdx.y;
    const vfloat4* base4 = (const vfloat4*)(side == 0 ? wf : bfeat);
    int* scnt = cnt + side * B;
    int* sidx = idxl + (size_t)side * B * CAP;
    float* sval = vall + (size_t)side * B * CAP;

    const size_t nf4 = (size_t)B * FEAT / 4;
    const size_t gstride = (size_t)gridDim.x * 256;
    for (size_t i4 = blockIdx.x * 256 + threadIdx.x; i4 < nf4; i4 += gstride) {
        const vfloat4 v = __builtin_nontemporal_load(base4 + i4);
        const bool any = (v.x != 0.f) | (v.y != 0.f) | (v.z != 0.f) | (v.w != 0.f);
        if (__any(any)) {
            const int e = (int)(i4 * 4);
            const int r = e / FEAT;              // magic-mul div (const divisor)
            const int c = e - r * FEAT;
            if (v.x != 0.f) { int p = atomicAdd(&scnt[r], 1); if (p < CAP) { sidx[r * CAP + p] = c + 0; sval[r * CAP + p] = v.x; } }
            if (v.y != 0.f) { int p = atomicAdd(&scnt[r], 1); if (p < CAP) { sidx[r * CAP + p] = c + 1; sval[r * CAP + p] = v.y; } }
            if (v.z != 0.f) { int p = atomicAdd(&scnt[r], 1); if (p < CAP) { sidx[r * CAP + p] = c + 2; sval[r * CAP + p] = v.z; } }
            if (v.w != 0.f) { int p = atomicAdd(&scnt[r], 1); if (p < CAP) { sidx[r * CAP + p] = c + 3; sval[r * CAP + p] = v.w; } }
        }
    }
}

// ---------------------------------------------------------------------------
// Kernel C: gather + MLP. One 256-thread block per batch row.
// ---------------------------------------------------------------------------
__global__ __launch_bounds__(256) void nnue_mlp(
    const int*   __restrict__ cnt,
    const int*   __restrict__ idxl,
    const float* __restrict__ vall,
    const float* __restrict__ ft_wt,  // [40960][256]
    const float* __restrict__ ft_b,
    const float* __restrict__ fc1_w,
    const float* __restrict__ fc1_b,
    const float* __restrict__ fc2_w,
    const float* __restrict__ fc2_b,
    const float* __restrict__ fc3_w,
    const float* __restrict__ fc3_b,
    float* __restrict__ out,
    int B)
{
    __shared__ int   idxw[CAP], idxb[CAP];
    __shared__ float valw[CAP], valb[CAP];
    __shared__ float xsh[512];
    __shared__ float red[256];
    __shared__ float h1[32], h2[32];

    const int tid = threadIdx.x;
    const int b   = blockIdx.x;

    const int nw = min(cnt[b],     CAP);
    const int nb = min(cnt[B + b], CAP);
    if (tid < CAP) {
        idxw[tid] = idxl[(size_t)b * CAP + tid];
        valw[tid] = vall[(size_t)b * CAP + tid];
        idxb[tid] = idxl[(size_t)(B + b) * CAP + tid];
        valb[tid] = vall[(size_t)(B + b) * CAP + tid];
    }
    __syncthreads();

    // gather-sum, white/black interleaved, 2-way unrolled: 4 loads in flight
    float aw0 = ft_b[tid], aw1 = 0.f;
    float ab0 = aw0,       ab1 = 0.f;
    const int nmin = min(nw, nb);
    int j = 0;
    for (; j + 2 <= nmin; j += 2) {
        const float w0 = ft_wt[(size_t)idxw[j]     * NH1 + tid];
        const float w1 = ft_wt[(size_t)idxw[j + 1] * NH1 + tid];
        const float b0 = ft_wt[(size_t)idxb[j]     * NH1 + tid];
        const float b1 = ft_wt[(size_t)idxb[j + 1] * NH1 + tid];
        aw0 += valw[j] * w0;  aw1 += valw[j + 1] * w1;
        ab0 += valb[j] * b0;  ab1 += valb[j + 1] * b1;
    }
    for (int jw = j; jw < nw; ++jw) aw0 += valw[jw] * ft_wt[(size_t)idxw[jw] * NH1 + tid];
    for (int jb = j; jb < nb; ++jb) ab0 += valb[jb] * ft_wt[(size_t)idxb[jb] * NH1 + tid];

    xsh[tid]       = fminf(fmaxf(aw0 + aw1, 0.f), 1.f);
    xsh[256 + tid] = fminf(fmaxf(ab0 + ab1, 0.f), 1.f);
    __syncthreads();

    // fc1 (512 -> 32): 8 partial threads per output
    {
        const int o = tid & 31, part = tid >> 5;
        const float* wrow = fc1_w + o * 512 + part * 64;
        const float* xp   = xsh + part * 64;
        float s = 0.f;
#pragma unroll
        for (int k = 0; k < 64; ++k) s += wrow[k] * xp[k];
        red[tid] = s;
    }
    __syncthreads();
    if (tid < 32) {
        float s = fc1_b[tid];
#pragma unroll
        for (int p = 0; p < 8; ++p) s += red[tid + p * 32];
        h1[tid] = fminf(fmaxf(s, 0.f), 1.f);
    }
    __syncthreads();

    // fc2 (32 -> 32)
    if (tid < 32) {
        float s = fc2_b[tid];
#pragma unroll
        for (int k = 0; k < 32; ++k) s += fc2_w[tid * 32 + k] * h1[k];
        h2[tid] = fminf(fmaxf(s, 0.f), 1.f);
    }
    __syncthreads();

    // fc3 (32 -> 1)
    if (tid == 0) {
        float s = fc3_b[0];
#pragma unroll
        for (int k = 0; k < 32; ++k) s += fc3_w[k] * h2[k];
        out[b] = s;
    }
}

// ---------------------------------------------------------------------------
extern "C" void kernel_launch(void* const* d_in, const int* in_sizes, int n_in,
                              void* d_out, int out_size, void* d_ws, size_t ws_size,
                              hipStream_t stream) {
    const float* wf    = (const float*)d_in[0];
    const float* bfeat = (const float*)d_in[1];
    const float* ft_w  = (const float*)d_in[2];
    const float* ft_b  = (const float*)d_in[3];
    const float* fc1_w = (const float*)d_in[4];
    const float* fc1_b = (const float*)d_in[5];
    const float* fc2_w = (const float*)d_in[6];
    const float* fc2_b = (const float*)d_in[7];
    const float* fc3_w = (const float*)d_in[8];
    const float* fc3_b = (const float*)d_in[9];
    float* out = (float*)d_out;

    const int B = in_sizes[0] / FEAT;  // 4096

    // ws layout: ft_wt (42 MB) | cnt (2B ints) | idxl (2B*CAP ints) | vall
    char* ws = (char*)d_ws;
    float* ft_wt = (float*)ws;                       ws += (size_t)FEAT * NH1 * sizeof(float);
    int*   cnt   = (int*)ws;                         ws += (size_t)2 * B * sizeof(int);
    int*   idxl  = (int*)ws;                         ws += (size_t)2 * B * CAP * sizeof(int);
    float* vall  = (float*)ws;

    zero_cnt<<<(2 * B + 255) / 256, 256, 0, stream>>>(cnt, 2 * B);
    {
        dim3 blk(32, 8);
        dim3 grd(FEAT / 32, NH1 / 32);
        transpose_ftw<<<grd, blk, 0, stream>>>(ft_w, ft_wt);
    }
    {
        dim3 grd(2048, 2);   // y = side; pure grid-stride streaming in x
        scan_nz<<<grd, 256, 0, stream>>>(wf, bfeat, cnt, idxl, vall, B);
    }
    nnue_mlp<<<B, 256, 0, stream>>>(cnt, idxl, vall, ft_wt,
                                    ft_b, fc1_w, fc1_b, fc2_w, fc2_b,
                                    fc3_w, fc3_b, out, B);
}

// Round 6
// 1238.970 us; speedup vs baseline: 1.0602x; 1.0602x over previous
//
#include <hip/hip_runtime.h>
#include <hip/hip_bf16.h>

#define FEAT 40960
#define NH1  256
#define MAXNZ 128   // reference guarantees <=30 nonzeros/row; guard anyway

typedef float vfloat4 __attribute__((ext_vector_type(4)));

// ---------------------------------------------------------------------------
// Kernel A: transpose ft_w [256][40960] -> ft_wt [40960][256]
// ---------------------------------------------------------------------------
__global__ __launch_bounds__(256) void transpose_ftw(const float* __restrict__ ft_w,
                                                     float* __restrict__ ft_wt) {
    __shared__ float tile[32][33];           // +1 pad: no bank conflicts
    const int i0 = blockIdx.x * 32;          // feature dim
    const int h0 = blockIdx.y * 32;          // hidden dim
    const int tx = threadIdx.x;              // 0..31
    const int ty = threadIdx.y;              // 0..7
#pragma unroll
    for (int j = 0; j < 4; ++j) {
        tile[ty + j * 8][tx] = ft_w[(size_t)(h0 + ty + j * 8) * FEAT + i0 + tx];
    }
    __syncthreads();
#pragma unroll
    for (int j = 0; j < 4; ++j) {
        ft_wt[(size_t)(i0 + ty + j * 8) * NH1 + h0 + tx] = tile[tx][ty + j * 8];
    }
}

// ---------------------------------------------------------------------------
// Kernel B: fully fused NNUE forward, one 256-thread block per batch row.
// (Round-4 structure: best measured. Decoupled scan/MLP regressed — r5.)
// ---------------------------------------------------------------------------
__global__ __launch_bounds__(256) void nnue_fused(
    const float* __restrict__ wf,     // [B][40960]
    const float* __restrict__ bfeat,  // [B][40960]
    const float* __restrict__ ft_wt,  // [40960][256] transposed
    const float* __restrict__ ft_b,   // [256]
    const float* __restrict__ fc1_w,  // [32][512]
    const float* __restrict__ fc1_b,  // [32]
    const float* __restrict__ fc2_w,  // [32][32]
    const float* __restrict__ fc2_b,  // [32]
    const float* __restrict__ fc3_w,  // [1][32]
    const float* __restrict__ fc3_b,  // [1]
    float* __restrict__ out)          // [B]
{
    __shared__ int   idxw[MAXNZ], idxb[MAXNZ];
    __shared__ float valw[MAXNZ], valb[MAXNZ];
    __shared__ int   cntw, cntb;
    __shared__ float xsh[512];
    __shared__ float red[256];
    __shared__ float h1[32], h2[32];

    const int tid = threadIdx.x;
    const int b   = blockIdx.x;

    if (tid == 0) { cntw = 0; cntb = 0; }
    __syncthreads();

    // ---- Stage 1: scan both feature rows (nontemporal float4 — zero reuse),
    // compact nonzeros into LDS lists. Wave-uniform __any fast-path: a wave's
    // 256-element slab per side is all-zero ~83% of the time, so one
    // s_cbranch_execz skips all 8 append sections.
    const vfloat4* wf4 = (const vfloat4*)(wf    + (size_t)b * FEAT);
    const vfloat4* bf4 = (const vfloat4*)(bfeat + (size_t)b * FEAT);
    constexpr int ITERS = FEAT / 4 / 256;  // 40
#pragma unroll 4
    for (int it = 0; it < ITERS; ++it) {
        const int k4 = it * 256 + tid;
        const vfloat4 vw = __builtin_nontemporal_load(wf4 + k4);
        const vfloat4 vb = __builtin_nontemporal_load(bf4 + k4);
        const int base = k4 * 4;
        const bool anyw = (vw.x != 0.f) | (vw.y != 0.f) | (vw.z != 0.f) | (vw.w != 0.f);
        const bool anyb = (vb.x != 0.f) | (vb.y != 0.f) | (vb.z != 0.f) | (vb.w != 0.f);
        if (__any(anyw)) {
            if (vw.x != 0.f) { int p = atomicAdd(&cntw, 1); if (p < MAXNZ) { idxw[p] = base + 0; valw[p] = vw.x; } }
            if (vw.y != 0.f) { int p = atomicAdd(&cntw, 1); if (p < MAXNZ) { idxw[p] = base + 1; valw[p] = vw.y; } }
            if (vw.z != 0.f) { int p = atomicAdd(&cntw, 1); if (p < MAXNZ) { idxw[p] = base + 2; valw[p] = vw.z; } }
            if (vw.w != 0.f) { int p = atomicAdd(&cntw, 1); if (p < MAXNZ) { idxw[p] = base + 3; valw[p] = vw.w; } }
        }
        if (__any(anyb)) {
            if (vb.x != 0.f) { int p = atomicAdd(&cntb, 1); if (p < MAXNZ) { idxb[p] = base + 0; valb[p] = vb.x; } }
            if (vb.y != 0.f) { int p = atomicAdd(&cntb, 1); if (p < MAXNZ) { idxb[p] = base + 1; valb[p] = vb.y; } }
            if (vb.z != 0.f) { int p = atomicAdd(&cntb, 1); if (p < MAXNZ) { idxb[p] = base + 2; valb[p] = vb.z; } }
            if (vb.w != 0.f) { int p = atomicAdd(&cntb, 1); if (p < MAXNZ) { idxb[p] = base + 3; valb[p] = vb.w; } }
        }
    }
    __syncthreads();
    const int nw = min(cntw, MAXNZ);
    const int nb = min(cntb, MAXNZ);

    // ---- Stage 2: gather-sum into hidden unit tid. Interleave white/black
    // with 2-way unroll each: 4 outstanding L2/L3 loads per thread.
    float aw0 = ft_b[tid], aw1 = 0.f;
    float ab0 = aw0,       ab1 = 0.f;
    const int nmin = min(nw, nb);
    int j = 0;
    for (; j + 2 <= nmin; j += 2) {
        const float w0 = ft_wt[(size_t)idxw[j]     * NH1 + tid];
        const float w1 = ft_wt[(size_t)idxw[j + 1] * NH1 + tid];
        const float b0 = ft_wt[(size_t)idxb[j]     * NH1 + tid];
        const float b1 = ft_wt[(size_t)idxb[j + 1] * NH1 + tid];
        aw0 += valw[j] * w0;  aw1 += valw[j + 1] * w1;
        ab0 += valb[j] * b0;  ab1 += valb[j + 1] * b1;
    }
    for (int jw = j; jw < nw; ++jw) aw0 += valw[jw] * ft_wt[(size_t)idxw[jw] * NH1 + tid];
    for (int jb = j; jb < nb; ++jb) ab0 += valb[jb] * ft_wt[(size_t)idxb[jb] * NH1 + tid];

    xsh[tid]       = fminf(fmaxf(aw0 + aw1, 0.f), 1.f);
    xsh[256 + tid] = fminf(fmaxf(ab0 + ab1, 0.f), 1.f);
    __syncthreads();

    // ---- Stage 3: fc1 (512 -> 32), 8 partial-threads per output
    {
        const int o = tid & 31, part = tid >> 5;
        const float* wrow = fc1_w + o * 512 + part * 64;
        const float* xp   = xsh + part * 64;
        float s = 0.f;
#pragma unroll
        for (int k = 0; k < 64; ++k) s += wrow[k] * xp[k];
        red[tid] = s;
    }
    __syncthreads();
    if (tid < 32) {
        float s = fc1_b[tid];
#pragma unroll
        for (int p = 0; p < 8; ++p) s += red[tid + p * 32];
        h1[tid] = fminf(fmaxf(s, 0.f), 1.f);
    }
    __syncthreads();

    // ---- Stage 4: fc2 (32 -> 32)
    if (tid < 32) {
        float s = fc2_b[tid];
#pragma unroll
        for (int k = 0; k < 32; ++k) s += fc2_w[tid * 32 + k] * h1[k];
        h2[tid] = fminf(fmaxf(s, 0.f), 1.f);
    }
    __syncthreads();

    // ---- Stage 5: fc3 (32 -> 1)
    if (tid == 0) {
        float s = fc3_b[0];
#pragma unroll
        for (int k = 0; k < 32; ++k) s += fc3_w[k] * h2[k];
        out[b] = s;
    }
}

// ---------------------------------------------------------------------------
extern "C" void kernel_launch(void* const* d_in, const int* in_sizes, int n_in,
                              void* d_out, int out_size, void* d_ws, size_t ws_size,
                              hipStream_t stream) {
    const float* wf    = (const float*)d_in[0];
    const float* bfeat = (const float*)d_in[1];
    const float* ft_w  = (const float*)d_in[2];
    const float* ft_b  = (const float*)d_in[3];
    const float* fc1_w = (const float*)d_in[4];
    const float* fc1_b = (const float*)d_in[5];
    const float* fc2_w = (const float*)d_in[6];
    const float* fc2_b = (const float*)d_in[7];
    const float* fc3_w = (const float*)d_in[8];
    const float* fc3_b = (const float*)d_in[9];
    float* out = (float*)d_out;

    const int B = in_sizes[0] / FEAT;  // 4096
    float* ft_wt = (float*)d_ws;       // 42 MB of the ~2.7 GB ws

    {
        dim3 blk(32, 8);
        dim3 grd(FEAT / 32, NH1 / 32);
        transpose_ftw<<<grd, blk, 0, stream>>>(ft_w, ft_wt);
    }
    nnue_fused<<<B, 256, 0, stream>>>(wf, bfeat, ft_wt,
                                      ft_b, fc1_w, fc1_b, fc2_w, fc2_b,
                                      fc3_w, fc3_b, out);
}